// Round 2
// baseline (207.638 us; speedup 1.0000x reference)
//
#include <hip/hip_runtime.h>

#define B_ 4096
#define T_ 1024
#define H_ 15

// DPP helper. ctrl must be a compile-time constant.
// row_ror:n (ctrl 0x120+n): lane l reads lane (l-n)&15 within its 16-lane row.
// row_shr:n (ctrl 0x110+n): lane l reads lane l-n; lanes shifted-in get 0 (bound_ctrl).
template <int CTRL>
__device__ __forceinline__ float dpp_f(float v) {
  return __int_as_float(
      __builtin_amdgcn_update_dpp(0, __float_as_int(v), CTRL, 0xF, 0xF, true));
}

// min-waves/EU = 1: we run exactly 1 wave/SIMD by construction (65536 threads),
// so give the register allocator the full VGPR budget — round 1 showed the
// compiler capping at 28 VGPRs and bouncing wr[] through AGPRs otherwise.
__global__ __launch_bounds__(256, 1) void rnn_tanh_kernel(
    const float* __restrict__ x, const float* __restrict__ w_ih,
    const float* __restrict__ w_hh, const float* __restrict__ b_ih,
    const float* __restrict__ b_hh, const float* __restrict__ w_lin,
    const float* __restrict__ b_lin, float* __restrict__ out) {
  const int tid = threadIdx.x;
  const int lane = tid & 15;               // hidden row this lane owns (15 = pad)
  const int grp = tid >> 4;                // batch-group within block (0..15)
  const int b = blockIdx.x * 16 + grp;     // batch index

  // Scale the whole preactivation by 2*log2(e) so tanh needs only
  // v_exp_f32: tanh(a) = 1 - 2/(exp2(s*a)+1), s = 2/ln(2).
  const float S = 2.8853900817779268f;

  // Per-lane recurrent weights, permuted for the rotation schedule:
  // at rotation n, this lane sees h[(lane-n)&15], so it needs W[lane][(lane-n)&15].
  // Pad row 15 / col 15 with zeros so the pad lane stays exactly 0.
  float wr[16];
#pragma unroll
  for (int n = 0; n < 16; ++n) {
    const int c = (lane - n) & 15;
    wr[n] = (lane < H_ && c < H_) ? S * w_hh[lane * H_ + c] : 0.0f;
  }
  const float wih  = (lane < H_) ? S * w_ih[lane] : 0.0f;
  const float bias = (lane < H_) ? S * (b_ih[lane] + b_hh[lane]) : 0.0f;
  const float wlin = (lane < H_) ? w_lin[lane] : 0.0f;
  const float blin = b_lin[0];

  const float* xb = x + (size_t)b * T_;
  float* ob = out + (size_t)b * T_;

  float h = 0.0f;  // h[lane], lane 15 stays exactly 0 (zero weights keep it 0)

  auto step = [&](float xt) -> float {
    const float base = fmaf(xt, wih, bias);   // off the h critical path
    // a'[l] = S * (x*w_ih + biases + sum_j W[l][j] h[j]) via 16 row rotations,
    // split over 4 independent accumulator chains (dep depth 4).
    float a0 = fmaf(wr[0], h, base);
    float a1 = dpp_f<0x121>(h) * wr[1];
    float a2 = dpp_f<0x122>(h) * wr[2];
    float a3 = dpp_f<0x123>(h) * wr[3];
    a0 += dpp_f<0x124>(h) * wr[4];
    a1 += dpp_f<0x125>(h) * wr[5];
    a2 += dpp_f<0x126>(h) * wr[6];
    a3 += dpp_f<0x127>(h) * wr[7];
    a0 += dpp_f<0x128>(h) * wr[8];
    a1 += dpp_f<0x129>(h) * wr[9];
    a2 += dpp_f<0x12a>(h) * wr[10];
    a3 += dpp_f<0x12b>(h) * wr[11];
    a0 += dpp_f<0x12c>(h) * wr[12];
    a1 += dpp_f<0x12d>(h) * wr[13];
    a2 += dpp_f<0x12e>(h) * wr[14];
    a3 += dpp_f<0x12f>(h) * wr[15];
    const float a = (a0 + a1) + (a2 + a3);
    // tanh: e = exp(2a) via one v_exp_f32 (inputs pre-scaled); saturates
    // correctly at +/-inf (rcp(inf)=0 -> h=1; exp2(-inf)=0 -> h=-1).
    const float e = __builtin_amdgcn_exp2f(a);
    h = fmaf(-2.0f, __builtin_amdgcn_rcpf(e + 1.0f), 1.0f);
    // output head: sum_l h[l]*w_lin[l] + b_lin, row_shr butterfly; full sum
    // lands in lane 15. Off the recurrence critical path.
    float p = h * wlin;
    p = p + dpp_f<0x111>(p);
    p = p + dpp_f<0x112>(p);
    p = p + dpp_f<0x114>(p);
    p = p + dpp_f<0x118>(p);
    return p + blin;
  };

  // Depth-2 prefetch: next chunk is ~8 steps (>1000 cyc) ahead of use,
  // covering the ~900-cycle HBM miss latency.
  float4 x0 = *(const float4*)xb;
  float4 x1 = *(const float4*)(xb + 4);
  for (int t = 0; t < T_; t += 4) {
    const int tn = (t + 8 < T_) ? (t + 8) : 0;   // clamp: stay in-bounds
    const float4 x2 = *(const float4*)(xb + tn);
    const float o0 = step(x0.x);
    const float o1 = step(x0.y);
    const float o2 = step(x0.z);
    const float o3 = step(x0.w);
    if (lane == 15) *(float4*)(ob + t) = make_float4(o0, o1, o2, o3);
    x0 = x1;
    x1 = x2;
  }
}

extern "C" void kernel_launch(void* const* d_in, const int* in_sizes, int n_in,
                              void* d_out, int out_size, void* d_ws, size_t ws_size,
                              hipStream_t stream) {
  (void)in_sizes; (void)n_in; (void)out_size; (void)d_ws; (void)ws_size;
  rnn_tanh_kernel<<<B_ / 16, 256, 0, stream>>>(
      (const float*)d_in[0], (const float*)d_in[1], (const float*)d_in[2],
      (const float*)d_in[3], (const float*)d_in[4], (const float*)d_in[5],
      (const float*)d_in[6], (float*)d_out);
}

// Round 3
// 203.825 us; speedup vs baseline: 1.0187x; 1.0187x over previous
//
#include <hip/hip_runtime.h>

#define B_ 4096
#define T_ 1024
#define H_ 15

// DPP helper. ctrl must be a compile-time constant.
// row_ror:n (ctrl 0x120+n): lane l reads lane (l-n)&15 within its 16-lane row.
// row_shr:n (ctrl 0x110+n): lane l reads lane l-n; lanes shifted-in get 0 (bound_ctrl).
template <int CTRL>
__device__ __forceinline__ float dpp_f(float v) {
  return __int_as_float(
      __builtin_amdgcn_update_dpp(0, __float_as_int(v), CTRL, 0xF, 0xF, true));
}

// We run exactly 1 wave/SIMD by construction (65536 threads = 1024 waves on
// 1024 SIMDs). Rounds 1-2 showed the allocator capping at 28 VGPRs (wr[]
// bounced through AGPRs / rematerialized), serializing the whole recurrence.
// amdgpu_waves_per_eu(1,1) unlocks the full register budget for 1-wave
// residency; __launch_bounds__(256,1) demonstrably did not.
__global__ __attribute__((amdgpu_flat_work_group_size(256, 256),
                          amdgpu_waves_per_eu(1, 1)))
void rnn_tanh_kernel(
    const float* __restrict__ x, const float* __restrict__ w_ih,
    const float* __restrict__ w_hh, const float* __restrict__ b_ih,
    const float* __restrict__ b_hh, const float* __restrict__ w_lin,
    const float* __restrict__ b_lin, float* __restrict__ out) {
  const int tid = threadIdx.x;
  const int lane = tid & 15;               // hidden row this lane owns (15 = pad)
  const int grp = tid >> 4;                // batch-group within block (0..15)
  const int b = blockIdx.x * 16 + grp;     // batch index

  // Scale the whole preactivation by 2*log2(e) so tanh needs only
  // v_exp_f32: tanh(a) = 1 - 2/(exp2(s*a)+1), s = 2/ln(2).
  const float S = 2.8853900817779268f;

  // Per-lane recurrent weights, permuted for the rotation schedule:
  // at rotation n, this lane sees h[(lane-n)&15], so it needs W[lane][(lane-n)&15].
  // Pad row 15 / col 15 with zeros so the pad lane stays exactly 0.
  float wr[16];
#pragma unroll
  for (int n = 0; n < 16; ++n) {
    const int c = (lane - n) & 15;
    wr[n] = (lane < H_ && c < H_) ? S * w_hh[lane * H_ + c] : 0.0f;
  }
  float wih  = (lane < H_) ? S * w_ih[lane] : 0.0f;
  float bias = (lane < H_) ? S * (b_ih[lane] + b_hh[lane]) : 0.0f;
  float wlin = (lane < H_) ? w_lin[lane] : 0.0f;
  float blin = b_lin[0];

  // Pin loop-invariant state into arch VGPRs: opaque asm blocks both
  // rematerialization (per-step reloads) and AGPR demotion.
#pragma unroll
  for (int n = 0; n < 16; ++n) asm("" : "+v"(wr[n]));
  asm("" : "+v"(wih), "+v"(bias), "+v"(wlin), "+v"(blin));

  const float* xb = x + (size_t)b * T_;
  float* ob = out + (size_t)b * T_;

  float h = 0.0f;  // h[lane], lane 15 stays exactly 0 (zero weights keep it 0)

  auto step = [&](float xt) -> float {
    const float base = fmaf(xt, wih, bias);   // off the h critical path
    // a'[l] = S * (x*w_ih + biases + sum_j W[l][j] h[j]) via 16 row rotations,
    // split over 4 independent accumulator chains (dep depth 4).
    float a0 = fmaf(wr[0], h, base);
    float a1 = dpp_f<0x121>(h) * wr[1];
    float a2 = dpp_f<0x122>(h) * wr[2];
    float a3 = dpp_f<0x123>(h) * wr[3];
    a0 += dpp_f<0x124>(h) * wr[4];
    a1 += dpp_f<0x125>(h) * wr[5];
    a2 += dpp_f<0x126>(h) * wr[6];
    a3 += dpp_f<0x127>(h) * wr[7];
    a0 += dpp_f<0x128>(h) * wr[8];
    a1 += dpp_f<0x129>(h) * wr[9];
    a2 += dpp_f<0x12a>(h) * wr[10];
    a3 += dpp_f<0x12b>(h) * wr[11];
    a0 += dpp_f<0x12c>(h) * wr[12];
    a1 += dpp_f<0x12d>(h) * wr[13];
    a2 += dpp_f<0x12e>(h) * wr[14];
    a3 += dpp_f<0x12f>(h) * wr[15];
    const float a = (a0 + a1) + (a2 + a3);
    // tanh: e = exp(2a) via one v_exp_f32 (inputs pre-scaled); saturates
    // correctly at +/-inf (rcp(inf)=0 -> h=1; exp2(-inf)=0 -> h=-1).
    const float e = __builtin_amdgcn_exp2f(a);
    h = fmaf(-2.0f, __builtin_amdgcn_rcpf(e + 1.0f), 1.0f);
    // output head: sum_l h[l]*w_lin[l] + b_lin, row_shr butterfly; full sum
    // lands in lane 15. Off the recurrence critical path.
    float p = h * wlin;
    p = p + dpp_f<0x111>(p);
    p = p + dpp_f<0x112>(p);
    p = p + dpp_f<0x114>(p);
    p = p + dpp_f<0x118>(p);
    return p + blin;
  };

  // Depth-2 prefetch: next chunk is ~8 steps (>1000 cyc) ahead of use,
  // covering the ~900-cycle HBM miss latency.
  float4 x0 = *(const float4*)xb;
  float4 x1 = *(const float4*)(xb + 4);
  for (int t = 0; t < T_; t += 4) {
    const int tn = (t + 8 < T_) ? (t + 8) : 0;   // clamp: stay in-bounds
    const float4 x2 = *(const float4*)(xb + tn);
    const float o0 = step(x0.x);
    const float o1 = step(x0.y);
    const float o2 = step(x0.z);
    const float o3 = step(x0.w);
    if (lane == 15) *(float4*)(ob + t) = make_float4(o0, o1, o2, o3);
    x0 = x1;
    x1 = x2;
  }
}

extern "C" void kernel_launch(void* const* d_in, const int* in_sizes, int n_in,
                              void* d_out, int out_size, void* d_ws, size_t ws_size,
                              hipStream_t stream) {
  (void)in_sizes; (void)n_in; (void)out_size; (void)d_ws; (void)ws_size;
  rnn_tanh_kernel<<<B_ / 16, 256, 0, stream>>>(
      (const float*)d_in[0], (const float*)d_in[1], (const float*)d_in[2],
      (const float*)d_in[3], (const float*)d_in[4], (const float*)d_in[5],
      (const float*)d_in[6], (float*)d_out);
}